// Round 1
// baseline (42.767 us; speedup 1.0000x reference)
//
#include <hip/hip_runtime.h>
#include <stdint.h>

#define WW 19
#define NP 361
#define NWD 6

// ---- compile-time bit masks -------------------------------------------------
constexpr uint64_t valid_word(int w) {
  uint64_t m = 0;
  for (int b = 0; b < 64; ++b) { int p = w * 64 + b; if (p < NP) m |= (1ull << b); }
  return m;
}
constexpr uint64_t notcol_word(int w, int col) {
  uint64_t m = 0;
  for (int b = 0; b < 64; ++b) {
    int p = w * 64 + b;
    if (p < NP && (p % WW) != col) m |= (1ull << b);
  }
  return m;
}

__device__ constexpr uint64_t VALIDM[NWD] = {
    valid_word(0), valid_word(1), valid_word(2),
    valid_word(3), valid_word(4), valid_word(5)};
__device__ constexpr uint64_t NC0[NWD] = {
    notcol_word(0, 0), notcol_word(1, 0), notcol_word(2, 0),
    notcol_word(3, 0), notcol_word(4, 0), notcol_word(5, 0)};
__device__ constexpr uint64_t NC18[NWD] = {
    notcol_word(0, 18), notcol_word(1, 18), notcol_word(2, 18),
    notcol_word(3, 18), notcol_word(4, 18), notcol_word(5, 18)};

// ---- 384-bit shift helpers --------------------------------------------------
template <int S>
__device__ __forceinline__ void shlw(const uint64_t* m, uint64_t* r) {
  r[0] = m[0] << S;
#pragma unroll
  for (int i = 1; i < NWD; ++i) r[i] = (m[i] << S) | (m[i - 1] >> (64 - S));
}
template <int S>
__device__ __forceinline__ void shrw(const uint64_t* m, uint64_t* r) {
#pragma unroll
  for (int i = 0; i < NWD - 1; ++i) r[i] = (m[i] >> S) | (m[i + 1] << (64 - S));
  r[NWD - 1] = m[NWD - 1] >> S;
}

__device__ __forceinline__ void dilate6(const uint64_t* m, uint64_t* o) {
  uint64_t u[NWD], d[NWD], l[NWD], r[NWD];
  shlw<WW>(m, u);
  shrw<WW>(m, d);
  shlw<1>(m, l);
  shrw<1>(m, r);
#pragma unroll
  for (int i = 0; i < NWD; ++i)
    o[i] = u[i] | d[i] | (l[i] & NC0[i]) | (r[i] & NC18[i]);
}

// ---- kernel: one wave (64 lanes) per board ----------------------------------
__global__ __launch_bounds__(256) void go_features_kernel(
    const float* __restrict__ stones,   // [B,2,19,19]
    const int* __restrict__ cur,        // [B]
    const int* __restrict__ ko,         // [B,2]
    const int* __restrict__ zob,        // [2,19,19] (int32)
    const int* __restrict__ zturn,      // [2]
    const int* __restrict__ phash,      // [B]
    float* __restrict__ out, int B) {
  const int wid = threadIdx.x >> 6;
  const int lane = threadIdx.x & 63;
  const int b = blockIdx.x * 4 + wid;
  if (b >= B) return;

  const size_t NB = (size_t)B * NP;
  const float* sb = stones + (size_t)b * (2 * NP);

  // Build bitboards via ballot; accumulate zobrist hash per lane.
  uint64_t bm[NWD], wm[NWD];
  int acc = 0;
#pragma unroll
  for (int i = 0; i < NWD; ++i) {
    const int p = i * 64 + lane;
    const bool inb = p < NP;
    const float bv = inb ? sb[p] : 0.0f;
    const float wv = inb ? sb[NP + p] : 0.0f;
    const bool bs = bv > 0.5f;
    const bool ws = wv > 0.5f;
    bm[i] = __ballot(bs);
    wm[i] = __ballot(ws);
    const int zb = inb ? zob[p] : 0;
    const int zw = inb ? zob[NP + p] : 0;
    acc ^= zb & (bs ? -1 : 0);
    acc ^= zw & (ws ? -1 : 0);
  }

  const int cp = cur[b];
  uint64_t oppm[NWD], emp[NWD];
#pragma unroll
  for (int i = 0; i < NWD; ++i) {
    oppm[i] = (cp == 0) ? wm[i] : bm[i];
    emp[i] = ~(bm[i] | wm[i]) & VALIDM[i];
  }

  // Directional empty-neighbor masks.
  uint64_t ue[NWD], de[NWD], le[NWD], re[NWD];
  shlw<WW>(emp, ue);
  shrw<WW>(emp, de);
  shlw<1>(emp, le);
  shrw<1>(emp, re);
#pragma unroll
  for (int i = 0; i < NWD; ++i) {
    le[i] &= NC0[i];
    re[i] &= NC18[i];
  }

  // vulnerable = opponent stones with exactly one empty neighbor;
  // legal = empty & (libs > 0)
  uint64_t vul[NWD], legal[NWD];
#pragma unroll
  for (int i = 0; i < NWD; ++i) {
    const uint64_t s1 = ue[i] ^ de[i], c1 = ue[i] & de[i];
    const uint64_t s2 = le[i] ^ re[i], c2 = le[i] & re[i];
    const uint64_t one = (s1 ^ s2) & ~(c1 | c2 | (s1 & s2));
    vul[i] = oppm[i] & one;
    legal[i] = emp[i] & (ue[i] | de[i] | le[i] | re[i]);
  }

  // capture moves: empty points adjacent to a vulnerable stone
  uint64_t dv[NWD];
  dilate6(vul, dv);
#pragma unroll
  for (int i = 0; i < NWD; ++i) legal[i] |= emp[i] & dv[i];

  // ko point
  const int kr = ko[2 * b], kc = ko[2 * b + 1];
  const int kp = (kr >= 0) ? (kr * WW + kc) : -1;
#pragma unroll
  for (int i = 0; i < NWD; ++i) {
    const uint64_t bit =
        ((unsigned)(kp - i * 64) < 64u) ? (1ull << (kp - i * 64)) : 0ull;
    legal[i] &= ~bit;
  }

  // flood fill vulnerable seeds within opponent stones (cap 90 iters)
  uint64_t g[NWD];
#pragma unroll
  for (int i = 0; i < NWD; ++i) g[i] = vul[i];
  for (int it = 0; it < 90; ++it) {
    uint64_t dg[NWD], ex[NWD];
    dilate6(g, dg);
    uint64_t any = 0;
#pragma unroll
    for (int i = 0; i < NWD; ++i) {
      ex[i] = dg[i] & oppm[i] & ~g[i];
      any |= ex[i];
    }
    if (any == 0) break;
#pragma unroll
    for (int i = 0; i < NWD; ++i) g[i] |= ex[i];
  }

  // Extract per-point outputs, coalesced.
  float* outLib = out;
  float* outLeg = out + NB;
  float* outGrp = out + 2 * NB;
#pragma unroll
  for (int i = 0; i < NWD; ++i) {
    const int p = i * 64 + lane;
    if (p < NP) {
      const uint32_t l1 = (uint32_t)(ue[i] >> lane) & 1u;
      const uint32_t l2 = (uint32_t)(de[i] >> lane) & 1u;
      const uint32_t l3 = (uint32_t)(le[i] >> lane) & 1u;
      const uint32_t l4 = (uint32_t)(re[i] >> lane) & 1u;
      const size_t o = (size_t)b * NP + p;
      outLib[o] = (float)(l1 + l2 + l3 + l4);
      outLeg[o] = (float)((uint32_t)(legal[i] >> lane) & 1u);
      outGrp[o] = (float)((uint32_t)(g[i] >> lane) & 1u);
    }
  }

  // Hash: wave XOR-reduce, then combine with position hash and turn toggle.
#pragma unroll
  for (int off = 32; off > 0; off >>= 1) acc ^= __shfl_xor(acc, off, 64);
  if (lane == 0) {
    const int h = phash[b] ^ acc ^ zturn[0] ^ zturn[1];
    out[3 * NB + b] = (float)h;
  }
}

extern "C" void kernel_launch(void* const* d_in, const int* in_sizes, int n_in,
                              void* d_out, int out_size, void* d_ws,
                              size_t ws_size, hipStream_t stream) {
  const float* stones = (const float*)d_in[0];
  const int* cur = (const int*)d_in[1];
  const int* ko = (const int*)d_in[2];
  const int* zob = (const int*)d_in[3];
  const int* zturn = (const int*)d_in[4];
  const int* phash = (const int*)d_in[5];
  float* out = (float*)d_out;

  const int B = in_sizes[0] / (2 * NP);
  const int blocks = (B + 3) / 4;
  go_features_kernel<<<blocks, 256, 0, stream>>>(stones, cur, ko, zob, zturn,
                                                 phash, out, B);
}

// Round 2
// 40.583 us; speedup vs baseline: 1.0538x; 1.0538x over previous
//
#include <hip/hip_runtime.h>
#include <stdint.h>

#define WW 19
#define NP 361
#define NWD 6

// ---- compile-time bit masks -------------------------------------------------
constexpr uint64_t valid_word(int w) {
  uint64_t m = 0;
  for (int b = 0; b < 64; ++b) { int p = w * 64 + b; if (p < NP) m |= (1ull << b); }
  return m;
}
constexpr uint64_t notcol_word(int w, int col) {
  uint64_t m = 0;
  for (int b = 0; b < 64; ++b) {
    int p = w * 64 + b;
    if (p < NP && (p % WW) != col) m |= (1ull << b);
  }
  return m;
}

__device__ constexpr uint64_t VALIDM[NWD] = {
    valid_word(0), valid_word(1), valid_word(2),
    valid_word(3), valid_word(4), valid_word(5)};
__device__ constexpr uint64_t NC0[NWD] = {
    notcol_word(0, 0), notcol_word(1, 0), notcol_word(2, 0),
    notcol_word(3, 0), notcol_word(4, 0), notcol_word(5, 0)};
__device__ constexpr uint64_t NC18[NWD] = {
    notcol_word(0, 18), notcol_word(1, 18), notcol_word(2, 18),
    notcol_word(3, 18), notcol_word(4, 18), notcol_word(5, 18)};

// ---- per-word directional shift helpers (i is an unrolled constant) ---------
__device__ __forceinline__ uint64_t dil_u(const uint64_t* m, int i) {
  return (m[i] << WW) | (i > 0 ? m[i - 1] >> (64 - WW) : 0ull);
}
__device__ __forceinline__ uint64_t dil_d(const uint64_t* m, int i) {
  return (m[i] >> WW) | (i < 5 ? m[i + 1] << (64 - WW) : 0ull);
}
__device__ __forceinline__ uint64_t dil_l(const uint64_t* m, int i) {
  return ((m[i] << 1) | (i > 0 ? m[i - 1] >> 63 : 0ull)) & NC0[i];
}
__device__ __forceinline__ uint64_t dil_r(const uint64_t* m, int i) {
  return ((m[i] >> 1) | (i < 5 ? m[i + 1] << 63 : 0ull)) & NC18[i];
}
__device__ __forceinline__ uint64_t dil4(const uint64_t* m, int i) {
  return dil_u(m, i) | dil_d(m, i) | dil_l(m, i) | dil_r(m, i);
}

// ================= K0: pack stones -> bitboards, zobrist hash ================
// wave per board; coalesced loads; ballot builds the 6-word bitboards.
__global__ __launch_bounds__(256) void k0_pack_hash(
    const float* __restrict__ stones, const int* __restrict__ zob,
    const int* __restrict__ zturn, const int* __restrict__ phash,
    float* __restrict__ out, uint32_t* __restrict__ bbws, int B) {
  __shared__ uint32_t buf[4][24];
  const int wid = threadIdx.x >> 6;
  const int lane = threadIdx.x & 63;
  const int b = blockIdx.x * 4 + wid;
  if (b >= B) return;
  const float* sb = stones + (size_t)b * (2 * NP);
  int acc = 0;
#pragma unroll
  for (int i = 0; i < NWD; ++i) {
    const int p = i * 64 + lane;
    const bool inb = p < NP;
    const float bv = inb ? sb[p] : 0.0f;
    const float wv = inb ? sb[NP + p] : 0.0f;
    const bool bs = bv > 0.5f;
    const bool wsn = wv > 0.5f;
    const uint64_t bb = __ballot(bs);
    const uint64_t wb = __ballot(wsn);
    if (lane == 0) {
      buf[wid][2 * i + 0] = (uint32_t)bb;
      buf[wid][2 * i + 1] = (uint32_t)(bb >> 32);
      buf[wid][12 + 2 * i + 0] = (uint32_t)wb;
      buf[wid][12 + 2 * i + 1] = (uint32_t)(wb >> 32);
    }
    const int zb = inb ? zob[p] : 0;
    const int zw = inb ? zob[NP + p] : 0;
    acc ^= zb & (bs ? -1 : 0);
    acc ^= zw & (wsn ? -1 : 0);
  }
#pragma unroll
  for (int off = 32; off > 0; off >>= 1) acc ^= __shfl_xor(acc, off, 64);
  if (lane == 0) {
    const int h = phash[b] ^ acc ^ zturn[0] ^ zturn[1];
    out[3 * (size_t)B * NP + b] = (float)h;
  }
  if (lane < 24) bbws[(size_t)b * 24 + lane] = buf[wid][lane];
}

// ================= K1: one board per LANE — all bitboard algebra =============
__global__ __launch_bounds__(64) void k1_flood(
    const uint32_t* __restrict__ bbws, const int* __restrict__ cur,
    const int* __restrict__ ko, uint32_t* __restrict__ plws, int B) {
  const int b = blockIdx.x * 64 + threadIdx.x;
  if (b >= B) return;

  uint64_t bm[NWD], wm[NWD];
  const uint4* pb = (const uint4*)(bbws + (size_t)b * 24);
#pragma unroll
  for (int j = 0; j < 6; ++j) {
    const uint4 v = pb[j];
    const uint64_t lo = (uint64_t)v.x | ((uint64_t)v.y << 32);
    const uint64_t hi = (uint64_t)v.z | ((uint64_t)v.w << 32);
    if (j < 3) { bm[2 * j] = lo; bm[2 * j + 1] = hi; }
    else       { wm[2 * (j - 3)] = lo; wm[2 * (j - 3) + 1] = hi; }
  }

  const int cp = cur[b];
  uint64_t opp[NWD], emp[NWD];
#pragma unroll
  for (int i = 0; i < NWD; ++i) {
    opp[i] = (cp == 0) ? wm[i] : bm[i];
    emp[i] = ~(bm[i] | wm[i]) & VALIDM[i];
  }

  uint64_t L0[NWD], L1[NWD], L2[NWD], legal[NWD], vul[NWD];
#pragma unroll
  for (int i = 0; i < NWD; ++i) {
    const uint64_t u = dil_u(emp, i), d = dil_d(emp, i);
    const uint64_t l = dil_l(emp, i), r = dil_r(emp, i);
    const uint64_t s1 = u ^ d, c1 = u & d;
    const uint64_t s2 = l ^ r, c2 = l & r;
    const uint64_t cc = s1 & s2;
    L0[i] = s1 ^ s2;
    L1[i] = c1 ^ c2 ^ cc;
    L2[i] = (c1 & c2) | (cc & (c1 | c2));
    legal[i] = emp[i] & (u | d | l | r);
    vul[i] = opp[i] & L0[i] & ~L1[i];  // count==1 -> L0=1,L1=0 (L2 impossible)
  }

  // capture moves: empty adjacent to vulnerable
#pragma unroll
  for (int i = 0; i < NWD; ++i) legal[i] |= emp[i] & dil4(vul, i);

  // ko point
  const int2 kk = ((const int2*)ko)[b];
  const int kp = (kk.x >= 0) ? (kk.x * WW + kk.y) : -1;
#pragma unroll
  for (int i = 0; i < NWD; ++i) {
    const uint64_t bit =
        ((unsigned)(kp - i * 64) < 64u) ? (1ull << (kp - i * 64)) : 0ull;
    legal[i] &= ~bit;
  }

  // flood fill vulnerable seeds within opponent stones (cap 90)
  uint64_t g[NWD];
#pragma unroll
  for (int i = 0; i < NWD; ++i) g[i] = vul[i];
  for (int it = 0; it < 90; ++it) {
    uint64_t ex[NWD], any = 0;
#pragma unroll
    for (int i = 0; i < NWD; ++i) {
      ex[i] = dil4(g, i) & opp[i] & ~g[i];
      any |= ex[i];
    }
    if (!__any(any != 0ull)) break;
#pragma unroll
    for (int i = 0; i < NWD; ++i) g[i] |= ex[i];
  }

  // write 30 u64 record: L0,L1,L2,legal,g
  uint64_t rec[30];
#pragma unroll
  for (int i = 0; i < NWD; ++i) {
    rec[i] = L0[i];
    rec[6 + i] = L1[i];
    rec[12 + i] = L2[i];
    rec[18 + i] = legal[i];
    rec[24 + i] = g[i];
  }
  uint4* pw = (uint4*)(plws + (size_t)b * 60);
#pragma unroll
  for (int j = 0; j < 15; ++j) {
    uint4 v;
    v.x = (uint32_t)rec[2 * j];
    v.y = (uint32_t)(rec[2 * j] >> 32);
    v.z = (uint32_t)rec[2 * j + 1];
    v.w = (uint32_t)(rec[2 * j + 1] >> 32);
    pw[j] = v;
  }
}

// ================= K2: expand bitplanes -> float outputs =====================
__global__ __launch_bounds__(256) void k2_expand(
    const uint32_t* __restrict__ plws, float* __restrict__ out, int B) {
  const int wid = threadIdx.x >> 6;
  const int lane = threadIdx.x & 63;
  const int b = blockIdx.x * 4 + wid;
  if (b >= B) return;
  const size_t NB = (size_t)B * NP;
  const uint64_t* rec = (const uint64_t*)(plws + (size_t)b * 60);
  float* o0 = out + (size_t)b * NP;
#pragma unroll
  for (int i = 0; i < NWD; ++i) {
    const int p = i * 64 + lane;
    if (p < NP) {
      const uint32_t l0 = (uint32_t)(rec[i] >> lane) & 1u;
      const uint32_t l1 = (uint32_t)(rec[6 + i] >> lane) & 1u;
      const uint32_t l2 = (uint32_t)(rec[12 + i] >> lane) & 1u;
      o0[p] = (float)(l0 + 2u * l1 + 4u * l2);
      o0[NB + p] = (float)((uint32_t)(rec[18 + i] >> lane) & 1u);
      o0[2 * NB + p] = (float)((uint32_t)(rec[24 + i] >> lane) & 1u);
    }
  }
}

// ================= fallback: original single kernel (if ws too small) ========
__global__ __launch_bounds__(256) void go_fallback(
    const float* __restrict__ stones, const int* __restrict__ cur,
    const int* __restrict__ ko, const int* __restrict__ zob,
    const int* __restrict__ zturn, const int* __restrict__ phash,
    float* __restrict__ out, int B) {
  const int wid = threadIdx.x >> 6;
  const int lane = threadIdx.x & 63;
  const int b = blockIdx.x * 4 + wid;
  if (b >= B) return;
  const size_t NB = (size_t)B * NP;
  const float* sb = stones + (size_t)b * (2 * NP);
  uint64_t bm[NWD], wm[NWD];
  int acc = 0;
#pragma unroll
  for (int i = 0; i < NWD; ++i) {
    const int p = i * 64 + lane;
    const bool inb = p < NP;
    const float bv = inb ? sb[p] : 0.0f;
    const float wv = inb ? sb[NP + p] : 0.0f;
    const bool bs = bv > 0.5f, wsn = wv > 0.5f;
    bm[i] = __ballot(bs);
    wm[i] = __ballot(wsn);
    const int zb = inb ? zob[p] : 0;
    const int zw = inb ? zob[NP + p] : 0;
    acc ^= zb & (bs ? -1 : 0);
    acc ^= zw & (wsn ? -1 : 0);
  }
  const int cp = cur[b];
  uint64_t opp[NWD], emp[NWD];
#pragma unroll
  for (int i = 0; i < NWD; ++i) {
    opp[i] = (cp == 0) ? wm[i] : bm[i];
    emp[i] = ~(bm[i] | wm[i]) & VALIDM[i];
  }
  uint64_t ue[NWD], de[NWD], le[NWD], re[NWD], vul[NWD], legal[NWD];
#pragma unroll
  for (int i = 0; i < NWD; ++i) {
    ue[i] = dil_u(emp, i); de[i] = dil_d(emp, i);
    le[i] = dil_l(emp, i); re[i] = dil_r(emp, i);
  }
#pragma unroll
  for (int i = 0; i < NWD; ++i) {
    const uint64_t s1 = ue[i] ^ de[i], c1 = ue[i] & de[i];
    const uint64_t s2 = le[i] ^ re[i], c2 = le[i] & re[i];
    const uint64_t one = (s1 ^ s2) & ~(c1 | c2 | (s1 & s2));
    vul[i] = opp[i] & one;
    legal[i] = emp[i] & (ue[i] | de[i] | le[i] | re[i]);
  }
#pragma unroll
  for (int i = 0; i < NWD; ++i) legal[i] |= emp[i] & dil4(vul, i);
  const int kr = ko[2 * b], kc = ko[2 * b + 1];
  const int kp = (kr >= 0) ? (kr * WW + kc) : -1;
#pragma unroll
  for (int i = 0; i < NWD; ++i) {
    const uint64_t bit =
        ((unsigned)(kp - i * 64) < 64u) ? (1ull << (kp - i * 64)) : 0ull;
    legal[i] &= ~bit;
  }
  uint64_t g[NWD];
#pragma unroll
  for (int i = 0; i < NWD; ++i) g[i] = vul[i];
  for (int it = 0; it < 90; ++it) {
    uint64_t ex[NWD], any = 0;
#pragma unroll
    for (int i = 0; i < NWD; ++i) {
      ex[i] = dil4(g, i) & opp[i] & ~g[i];
      any |= ex[i];
    }
    if (any == 0) break;
#pragma unroll
    for (int i = 0; i < NWD; ++i) g[i] |= ex[i];
  }
#pragma unroll
  for (int i = 0; i < NWD; ++i) {
    const int p = i * 64 + lane;
    if (p < NP) {
      const uint32_t l1 = (uint32_t)(ue[i] >> lane) & 1u;
      const uint32_t l2 = (uint32_t)(de[i] >> lane) & 1u;
      const uint32_t l3 = (uint32_t)(le[i] >> lane) & 1u;
      const uint32_t l4 = (uint32_t)(re[i] >> lane) & 1u;
      const size_t o = (size_t)b * NP + p;
      out[o] = (float)(l1 + l2 + l3 + l4);
      out[NB + o] = (float)((uint32_t)(legal[i] >> lane) & 1u);
      out[2 * NB + o] = (float)((uint32_t)(g[i] >> lane) & 1u);
    }
  }
#pragma unroll
  for (int off = 32; off > 0; off >>= 1) acc ^= __shfl_xor(acc, off, 64);
  if (lane == 0) {
    const int h = phash[b] ^ acc ^ zturn[0] ^ zturn[1];
    out[3 * NB + b] = (float)h;
  }
}

extern "C" void kernel_launch(void* const* d_in, const int* in_sizes, int n_in,
                              void* d_out, int out_size, void* d_ws,
                              size_t ws_size, hipStream_t stream) {
  const float* stones = (const float*)d_in[0];
  const int* cur = (const int*)d_in[1];
  const int* ko = (const int*)d_in[2];
  const int* zob = (const int*)d_in[3];
  const int* zturn = (const int*)d_in[4];
  const int* phash = (const int*)d_in[5];
  float* out = (float*)d_out;

  const int B = in_sizes[0] / (2 * NP);
  const size_t need = (size_t)B * (96 + 240);  // bitboards + planes

  if (ws_size >= need) {
    uint32_t* bbws = (uint32_t*)d_ws;
    uint32_t* plws = bbws + (size_t)B * 24;
    k0_pack_hash<<<(B + 3) / 4, 256, 0, stream>>>(stones, zob, zturn, phash,
                                                  out, bbws, B);
    k1_flood<<<(B + 63) / 64, 64, 0, stream>>>(bbws, cur, ko, plws, B);
    k2_expand<<<(B + 3) / 4, 256, 0, stream>>>(plws, out, B);
  } else {
    go_fallback<<<(B + 3) / 4, 256, 0, stream>>>(stones, cur, ko, zob, zturn,
                                                 phash, out, B);
  }
}